// Round 4
// baseline (306.492 us; speedup 1.0000x reference)
//
#include <hip/hip_runtime.h>

#define H 1024
#define W 1024
#define NB 8
#define TY 8
#define NT 256

__global__ void ncc_zero(double* acc) { *acc = 0.0; }

__global__ void ncc_finalize(const double* __restrict__ acc, float* __restrict__ out) {
    out[0] = 1.0f - (float)(*acc * (1.0 / 8388608.0));  // 8*1024*1024 pixels
}

// Load 12 cols (x0-4 .. x0+7) of one row; halo cols masked by mlo/mhi.
// Addresses are pre-clamped so every load is in-bounds and float4-aligned.
__device__ __forceinline__ void load12(const float* __restrict__ p,
                                       int xlo, int x0, int xhi,
                                       float mlo, float mhi, float* f) {
    float4 lo = *(const float4*)(p + xlo);
    float4 md = *(const float4*)(p + x0);
    float4 hi = *(const float4*)(p + xhi);
    f[0] = lo.x * mlo; f[1] = lo.y * mlo; f[2]  = lo.z * mlo; f[3]  = lo.w * mlo;
    f[4] = md.x;       f[5] = md.y;       f[6]  = md.z;       f[7]  = md.w;
    f[8] = hi.x * mhi; f[9] = hi.y * mhi; f[10] = hi.z * mhi; f[11] = hi.w * mhi;
}

// 9-tap sliding horizontal sums of v: o[c] = sum(v[c..c+8])
__device__ __forceinline__ void hpass(const float* v, float* o) {
    float s = v[0] + v[1] + v[2] + v[3] + v[4] + v[5] + v[6] + v[7] + v[8];
    o[0] = s; s += v[9]  - v[0];
    o[1] = s; s += v[10] - v[1];
    o[2] = s; s += v[11] - v[2];
    o[3] = s;
}

// 9-tap sums of the elementwise product a[c]*b[c]; products inlined (short lifetimes)
__device__ __forceinline__ void hpass_p(const float* a, const float* b, float* o) {
    const float p0 = a[0]*b[0],  p1 = a[1]*b[1],  p2  = a[2]*b[2],  p3  = a[3]*b[3];
    const float p4 = a[4]*b[4],  p5 = a[5]*b[5],  p6  = a[6]*b[6],  p7  = a[7]*b[7];
    const float p8 = a[8]*b[8],  p9 = a[9]*b[9],  p10 = a[10]*b[10], p11 = a[11]*b[11];
    float s = p0 + p1 + p2 + p3 + p4 + p5 + p6 + p7 + p8;
    o[0] = s; s += p9  - p0;
    o[1] = s; s += p10 - p1;
    o[2] = s; s += p11 - p2;
    o[3] = s;
}

__global__ __launch_bounds__(NT, 4) void ncc_main(
    const float* __restrict__ Jg,  // y_pred
    const float* __restrict__ Ig,  // y_true
    double* __restrict__ acc)
{
    const int b  = blockIdx.x;
    const int y0 = blockIdx.y * TY;
    const int t  = threadIdx.x;
    const int x0 = t << 2;                       // 4 output cols per thread

    const int   xlo = max(x0 - 4, 0);
    const int   xhi = min(x0 + 4, W - 4);
    const float mlo = (x0 >= 4)     ? 1.0f : 0.0f;
    const float mhi = (x0 <= W - 8) ? 1.0f : 0.0f;

    const float* __restrict__ Ib = Ig + (size_t)b * (H * W);
    const float* __restrict__ Jb = Jg + (size_t)b * (H * W);

    // vertical running sums of per-row horizontal 9-tap sums: 5 quantities x 4 cols
    float rI[4]  = {0,0,0,0}, rJ[4] = {0,0,0,0}, rII[4] = {0,0,0,0};
    float rJJ[4] = {0,0,0,0}, rIJ[4] = {0,0,0,0};

    // ---- initial vertical window: rows y0-4 .. y0+4 (row-masked, unconditional loads)
    #pragma unroll
    for (int k = -4; k <= 4; ++k) {
        const int   r  = y0 + k;
        const float m  = ((unsigned)r < (unsigned)H) ? 1.0f : 0.0f;
        const int   rc = min(max(r, 0), H - 1);
        float fi[12], fj[12];
        load12(Ib + (size_t)rc * W, xlo, x0, xhi, mlo, mhi, fi);
        load12(Jb + (size_t)rc * W, xlo, x0, xhi, mlo, mhi, fj);
        float hI[4], hJ[4], hII[4], hJJ[4], hIJ[4];
        hpass(fi, hI);
        hpass(fj, hJ);
        hpass_p(fi, fi, hII);
        hpass_p(fj, fj, hJJ);
        hpass_p(fi, fj, hIJ);
        #pragma unroll
        for (int c = 0; c < 4; ++c) {
            rI[c]  = fmaf(m, hI[c],  rI[c]);
            rJ[c]  = fmaf(m, hJ[c],  rJ[c]);
            rII[c] = fmaf(m, hII[c], rII[c]);
            rJJ[c] = fmaf(m, hJJ[c], rJJ[c]);
            rIJ[c] = fmaf(m, hIJ[c], rIJ[c]);
        }
    }

    const float inv = 1.0f / 81.0f;
    float accv = 0.0f;

    #pragma unroll 1
    for (int y = y0; y < y0 + TY; ++y) {
        const int   ra  = y + 5;                       // entering row
        const int   rs  = y - 4;                       // leaving row
        const float ma  = (ra < H)  ? 1.0f : 0.0f;
        const float ms  = (rs >= 0) ? 1.0f : 0.0f;
        const int   rca = min(ra, H - 1);
        const int   rcs = max(rs, 0);

        // 1) issue all slide loads (unconditional -> stays in registers, overlaps cc math)
        float fia[12], fja[12], fis[12], fjs[12];
        load12(Ib + (size_t)rca * W, xlo, x0, xhi, mlo, mhi, fia);
        load12(Jb + (size_t)rca * W, xlo, x0, xhi, mlo, mhi, fja);
        load12(Ib + (size_t)rcs * W, xlo, x0, xhi, mlo, mhi, fis);
        load12(Jb + (size_t)rcs * W, xlo, x0, xhi, mlo, mhi, fjs);

        // 2) per-pixel cc for current row y from running sums (independent of the loads)
        #pragma unroll
        for (int c = 0; c < 4; ++c) {
            const float uI    = rI[c] * inv;
            const float uJ    = rJ[c] * inv;
            const float cross = rIJ[c] * inv - uI * uJ;
            const float Iv    = rII[c] * inv - uI * uI;
            const float Jv    = rJJ[c] * inv - uJ * uJ;
            accv += cross * rsqrtf(fmaxf(Iv * Jv, 1e-7f));
        }

        // 3) entering row's horizontal sums -> accumulate (frees fia/fja early)
        {
            float hI[4], hJ[4], hII[4], hJJ[4], hIJ[4];
            hpass(fia, hI);
            hpass(fja, hJ);
            hpass_p(fia, fia, hII);
            hpass_p(fja, fja, hJJ);
            hpass_p(fia, fja, hIJ);
            #pragma unroll
            for (int c = 0; c < 4; ++c) {
                rI[c]  = fmaf(ma, hI[c],  rI[c]);
                rJ[c]  = fmaf(ma, hJ[c],  rJ[c]);
                rII[c] = fmaf(ma, hII[c], rII[c]);
                rJJ[c] = fmaf(ma, hJJ[c], rJJ[c]);
                rIJ[c] = fmaf(ma, hIJ[c], rIJ[c]);
            }
        }
        // 4) leaving row's horizontal sums -> subtract
        {
            float hI[4], hJ[4], hII[4], hJJ[4], hIJ[4];
            hpass(fis, hI);
            hpass(fjs, hJ);
            hpass_p(fis, fis, hII);
            hpass_p(fjs, fjs, hJJ);
            hpass_p(fis, fjs, hIJ);
            #pragma unroll
            for (int c = 0; c < 4; ++c) {
                rI[c]  = fmaf(-ms, hI[c],  rI[c]);
                rJ[c]  = fmaf(-ms, hJ[c],  rJ[c]);
                rII[c] = fmaf(-ms, hII[c], rII[c]);
                rJJ[c] = fmaf(-ms, hJJ[c], rJJ[c]);
                rIJ[c] = fmaf(-ms, hIJ[c], rIJ[c]);
            }
        }
    }

    // wave reduction (64 lanes), one double atomic per wave
    #pragma unroll
    for (int off = 32; off > 0; off >>= 1)
        accv += __shfl_down(accv, off);
    if ((t & 63) == 0)
        atomicAdd(acc, (double)accv);
}

extern "C" void kernel_launch(void* const* d_in, const int* in_sizes, int n_in,
                              void* d_out, int out_size, void* d_ws, size_t ws_size,
                              hipStream_t stream) {
    const float* y_pred = (const float*)d_in[0];  // Ji
    const float* y_true = (const float*)d_in[1];  // Ii
    float* out = (float*)d_out;
    double* accp = (double*)d_ws;

    ncc_zero<<<dim3(1), dim3(1), 0, stream>>>(accp);
    dim3 grid(NB, H / TY);  // 8 x 128 = 1024 blocks; no LDS, no barriers, no shuffles in hot loop
    ncc_main<<<grid, dim3(NT), 0, stream>>>(y_pred, y_true, accp);
    ncc_finalize<<<dim3(1), dim3(1), 0, stream>>>(accp, out);
}

// Round 5
// 78.337 us; speedup vs baseline: 3.9125x; 3.9125x over previous
//
#include <hip/hip_runtime.h>

#define H 1024
#define W 1024
#define NB 8
#define TY 8
#define NT 256

__global__ void ncc_zero(double* acc) { *acc = 0.0; }

__global__ void ncc_finalize(const double* __restrict__ acc, float* __restrict__ out) {
    out[0] = 1.0f - (float)(*acc * (1.0 / 8388608.0));  // 8*1024*1024 pixels
}

// Load 12 cols (x0-4 .. x0+7) of one row into f[12]; halo cols masked by mlo/mhi.
// Addresses pre-clamped -> always in-bounds, float4-aligned.
#define LOAD12(base, f) do {                                                          \
    float4 lo_ = *(const float4*)((base) + xlo);                                      \
    float4 md_ = *(const float4*)((base) + x0);                                       \
    float4 hi_ = *(const float4*)((base) + xhi);                                      \
    f[0] = lo_.x * mlo; f[1] = lo_.y * mlo; f[2]  = lo_.z * mlo; f[3]  = lo_.w * mlo; \
    f[4] = md_.x;       f[5] = md_.y;       f[6]  = md_.z;       f[7]  = md_.w;       \
    f[8] = hi_.x * mhi; f[9] = hi_.y * mhi; f[10] = hi_.z * mhi; f[11] = hi_.w * mhi; \
} while (0)

// 9-tap sliding horizontal sums: o[c] = sum(v[c..c+8]), c=0..3
#define HP(v, o) do {                                                   \
    float s_ = v[0]+v[1]+v[2]+v[3]+v[4]+v[5]+v[6]+v[7]+v[8];            \
    o[0] = s_; s_ += v[9]  - v[0];                                      \
    o[1] = s_; s_ += v[10] - v[1];                                      \
    o[2] = s_; s_ += v[11] - v[2];                                      \
    o[3] = s_;                                                          \
} while (0)

#define PROD12(a, b, p) do {                                            \
    p[0]=a[0]*b[0]; p[1]=a[1]*b[1]; p[2] =a[2]*b[2];   p[3] =a[3]*b[3]; \
    p[4]=a[4]*b[4]; p[5]=a[5]*b[5]; p[6] =a[6]*b[6];   p[7] =a[7]*b[7]; \
    p[8]=a[8]*b[8]; p[9]=a[9]*b[9]; p[10]=a[10]*b[10]; p[11]=a[11]*b[11];\
} while (0)

#define ACC4(r, h, m) do {                                              \
    r[0]=fmaf(m,h[0],r[0]); r[1]=fmaf(m,h[1],r[1]);                     \
    r[2]=fmaf(m,h[2],r[2]); r[3]=fmaf(m,h[3],r[3]);                     \
} while (0)

// fold one row (fi,fj = 12-col slices of I and J) into the 20 running sums, scaled by m
#define ROW_ACC(fi, fj, m) do {                                               \
    { float h_[4]; HP(fi, h_); ACC4(rI, h_, m); }                             \
    { float h_[4]; HP(fj, h_); ACC4(rJ, h_, m); }                             \
    { float p_[12], h_[4]; PROD12(fi, fi, p_); HP(p_, h_); ACC4(rII, h_, m); }\
    { float p_[12], h_[4]; PROD12(fj, fj, p_); HP(p_, h_); ACC4(rJJ, h_, m); }\
    { float p_[12], h_[4]; PROD12(fi, fj, p_); HP(p_, h_); ACC4(rIJ, h_, m); }\
} while (0)

__global__ __launch_bounds__(NT) void ncc_main(
    const float* __restrict__ Jg,  // y_pred
    const float* __restrict__ Ig,  // y_true
    double* __restrict__ acc)
{
    const int b  = blockIdx.x;
    const int y0 = blockIdx.y * TY;
    const int t  = threadIdx.x;
    const int x0 = t << 2;                       // 4 output cols per thread

    const int   xlo = max(x0 - 4, 0);
    const int   xhi = min(x0 + 4, W - 4);
    const float mlo = (x0 >= 4)     ? 1.0f : 0.0f;
    const float mhi = (x0 <= W - 8) ? 1.0f : 0.0f;

    const float* __restrict__ Ib = Ig + (size_t)b * (H * W);
    const float* __restrict__ Jb = Jg + (size_t)b * (H * W);

    // vertical running sums of per-row horizontal 9-tap sums: 5 quantities x 4 cols
    float rI[4]  = {0,0,0,0}, rJ[4] = {0,0,0,0}, rII[4] = {0,0,0,0};
    float rJJ[4] = {0,0,0,0}, rIJ[4] = {0,0,0,0};

    // initial vertical window: rows y0-4 .. y0+4 (row-masked, one row live at a time)
    #pragma unroll 1
    for (int k = -4; k <= 4; ++k) {
        const int   r  = y0 + k;
        const float m  = ((unsigned)r < (unsigned)H) ? 1.0f : 0.0f;
        const int   rc = min(max(r, 0), H - 1);
        float fi_[12], fj_[12];
        LOAD12(Ib + (size_t)rc * W, fi_);
        LOAD12(Jb + (size_t)rc * W, fj_);
        ROW_ACC(fi_, fj_, m);
    }

    const float inv = 1.0f / 81.0f;
    float accv = 0.0f;

    #pragma unroll 1
    for (int y = y0; y < y0 + TY; ++y) {
        const int   ra  = y + 5;                   // entering row
        const int   rs  = y - 4;                   // leaving row
        const float ma  = (ra < H)  ?  1.0f : 0.0f;
        const float msn = (rs >= 0) ? -1.0f : 0.0f;
        const int   rca = min(ra, H - 1);
        const int   rcs = max(rs, 0);

        // issue entering-row loads (HBM-cold) first...
        float fa_[12], fb_[12];
        LOAD12(Ib + (size_t)rca * W, fa_);
        LOAD12(Jb + (size_t)rca * W, fb_);

        // ...hide their latency under cc math for current row y (uses only running sums)
        #pragma unroll
        for (int c = 0; c < 4; ++c) {
            const float uI    = rI[c] * inv;
            const float uJ    = rJ[c] * inv;
            const float cross = rIJ[c] * inv - uI * uJ;
            const float Iv    = rII[c] * inv - uI * uI;
            const float Jv    = rJJ[c] * inv - uJ * uJ;
            accv += cross * rsqrtf(fmaxf(Iv * Jv, 1e-7f));
        }

        // fold entering row in (frees fa_/fb_)
        ROW_ACC(fa_, fb_, ma);

        // leaving row: read 9 rows ago by this same block -> L1/L2 hit
        float fs_[12], ft_[12];
        LOAD12(Ib + (size_t)rcs * W, fs_);
        LOAD12(Jb + (size_t)rcs * W, ft_);
        ROW_ACC(fs_, ft_, msn);
    }

    // wave reduction (64 lanes), one double atomic per wave
    #pragma unroll
    for (int off = 32; off > 0; off >>= 1)
        accv += __shfl_down(accv, off);
    if ((t & 63) == 0)
        atomicAdd(acc, (double)accv);
}

extern "C" void kernel_launch(void* const* d_in, const int* in_sizes, int n_in,
                              void* d_out, int out_size, void* d_ws, size_t ws_size,
                              hipStream_t stream) {
    const float* y_pred = (const float*)d_in[0];  // Ji
    const float* y_true = (const float*)d_in[1];  // Ii
    float* out = (float*)d_out;
    double* accp = (double*)d_ws;

    ncc_zero<<<dim3(1), dim3(1), 0, stream>>>(accp);
    dim3 grid(NB, H / TY);  // 8 x 128 = 1024 blocks; no LDS, no barriers, macro/inline only
    ncc_main<<<grid, dim3(NT), 0, stream>>>(y_pred, y_true, accp);
    ncc_finalize<<<dim3(1), dim3(1), 0, stream>>>(accp, out);
}

// Round 6
// 55.155 us; speedup vs baseline: 5.5569x; 1.4203x over previous
//
#include <hip/hip_runtime.h>

#define H 1024
#define W 1024
#define NB 8
#define TY 4
#define NT 256

__global__ void ncc_zero(double* acc) { *acc = 0.0; }

__global__ void ncc_finalize(const double* __restrict__ acc, float* __restrict__ out) {
    out[0] = 1.0f - (float)(*acc * (1.0 / 8388608.0));  // 8*1024*1024 pixels
}

// Load 12 cols (x0-4 .. x0+7) of one row into f[12]; halo cols masked by mlo/mhi.
// Addresses pre-clamped -> always in-bounds, float4-aligned.
#define LOAD12(base, f) do {                                                          \
    float4 lo_ = *(const float4*)((base) + xlo);                                      \
    float4 md_ = *(const float4*)((base) + x0);                                       \
    float4 hi_ = *(const float4*)((base) + xhi);                                      \
    f[0] = lo_.x * mlo; f[1] = lo_.y * mlo; f[2]  = lo_.z * mlo; f[3]  = lo_.w * mlo; \
    f[4] = md_.x;       f[5] = md_.y;       f[6]  = md_.z;       f[7]  = md_.w;       \
    f[8] = hi_.x * mhi; f[9] = hi_.y * mhi; f[10] = hi_.z * mhi; f[11] = hi_.w * mhi; \
} while (0)

// 9-tap sliding horizontal sums: o[c] = sum(v[c..c+8]), c=0..3
#define HP(v, o) do {                                                   \
    float s_ = v[0]+v[1]+v[2]+v[3]+v[4]+v[5]+v[6]+v[7]+v[8];            \
    o[0] = s_; s_ += v[9]  - v[0];                                      \
    o[1] = s_; s_ += v[10] - v[1];                                      \
    o[2] = s_; s_ += v[11] - v[2];                                      \
    o[3] = s_;                                                          \
} while (0)

#define PROD12(a, b, p) do {                                            \
    p[0]=a[0]*b[0]; p[1]=a[1]*b[1]; p[2] =a[2]*b[2];   p[3] =a[3]*b[3]; \
    p[4]=a[4]*b[4]; p[5]=a[5]*b[5]; p[6] =a[6]*b[6];   p[7] =a[7]*b[7]; \
    p[8]=a[8]*b[8]; p[9]=a[9]*b[9]; p[10]=a[10]*b[10]; p[11]=a[11]*b[11];\
} while (0)

#define ACC4(r, h, m) do {                                              \
    r[0]=fmaf(m,h[0],r[0]); r[1]=fmaf(m,h[1],r[1]);                     \
    r[2]=fmaf(m,h[2],r[2]); r[3]=fmaf(m,h[3],r[3]);                     \
} while (0)

// fold one row (fi,fj = 12-col slices of I and J) into the 20 running sums, scaled by m
#define ROW_ACC(fi, fj, m) do {                                               \
    { float h_[4]; HP(fi, h_); ACC4(rI, h_, m); }                             \
    { float h_[4]; HP(fj, h_); ACC4(rJ, h_, m); }                             \
    { float p_[12], h_[4]; PROD12(fi, fi, p_); HP(p_, h_); ACC4(rII, h_, m); }\
    { float p_[12], h_[4]; PROD12(fj, fj, p_); HP(p_, h_); ACC4(rJJ, h_, m); }\
    { float p_[12], h_[4]; PROD12(fi, fj, p_); HP(p_, h_); ACC4(rIJ, h_, m); }\
} while (0)

__global__ __launch_bounds__(NT) void ncc_main(
    const float* __restrict__ Jg,  // y_pred
    const float* __restrict__ Ig,  // y_true
    double* __restrict__ acc)
{
    __shared__ double sred[NT / 64];

    const int b  = blockIdx.x;
    const int y0 = blockIdx.y * TY;
    const int t  = threadIdx.x;
    const int x0 = t << 2;                       // 4 output cols per thread

    const int   xlo = max(x0 - 4, 0);
    const int   xhi = min(x0 + 4, W - 4);
    const float mlo = (x0 >= 4)     ? 1.0f : 0.0f;
    const float mhi = (x0 <= W - 8) ? 1.0f : 0.0f;

    const float* __restrict__ Ib = Ig + (size_t)b * (H * W);
    const float* __restrict__ Jb = Jg + (size_t)b * (H * W);

    // vertical running sums of per-row horizontal 9-tap sums: 5 quantities x 4 cols
    float rI[4]  = {0,0,0,0}, rJ[4] = {0,0,0,0}, rII[4] = {0,0,0,0};
    float rJJ[4] = {0,0,0,0}, rIJ[4] = {0,0,0,0};

    // initial vertical window: rows y0-4 .. y0+4 (row-masked, one row live at a time)
    #pragma unroll 1
    for (int k = -4; k <= 4; ++k) {
        const int   r  = y0 + k;
        const float m  = ((unsigned)r < (unsigned)H) ? 1.0f : 0.0f;
        const int   rc = min(max(r, 0), H - 1);
        float fi_[12], fj_[12];
        LOAD12(Ib + (size_t)rc * W, fi_);
        LOAD12(Jb + (size_t)rc * W, fj_);
        ROW_ACC(fi_, fj_, m);
    }

    const float inv = 1.0f / 81.0f;
    float accv = 0.0f;

    #pragma unroll 1
    for (int y = y0; y < y0 + TY; ++y) {
        const int   ra  = y + 5;                   // entering row
        const int   rs  = y - 4;                   // leaving row
        const float ma  = (ra < H)  ?  1.0f : 0.0f;
        const float msn = (rs >= 0) ? -1.0f : 0.0f;
        const int   rca = min(ra, H - 1);
        const int   rcs = max(rs, 0);

        // issue entering-row loads (HBM-cold) first...
        float fa_[12], fb_[12];
        LOAD12(Ib + (size_t)rca * W, fa_);
        LOAD12(Jb + (size_t)rca * W, fb_);

        // ...hide their latency under cc math for current row y (uses only running sums)
        #pragma unroll
        for (int c = 0; c < 4; ++c) {
            const float uI    = rI[c] * inv;
            const float uJ    = rJ[c] * inv;
            const float cross = rIJ[c] * inv - uI * uJ;
            const float Iv    = rII[c] * inv - uI * uI;
            const float Jv    = rJJ[c] * inv - uJ * uJ;
            accv += cross * rsqrtf(fmaxf(Iv * Jv, 1e-7f));
        }

        // fold entering row in (frees fa_/fb_)
        ROW_ACC(fa_, fb_, ma);

        // leaving row: read 9 rows ago by this same block -> L2 hit
        float fs_[12], ft_[12];
        LOAD12(Ib + (size_t)rcs * W, fs_);
        LOAD12(Jb + (size_t)rcs * W, ft_);
        ROW_ACC(fs_, ft_, msn);
    }

    // wave reduction (64 lanes) -> LDS -> one atomic per block
    #pragma unroll
    for (int off = 32; off > 0; off >>= 1)
        accv += __shfl_down(accv, off);
    if ((t & 63) == 0)
        sred[t >> 6] = (double)accv;
    __syncthreads();
    if (t == 0) {
        double s = sred[0];
        #pragma unroll
        for (int w = 1; w < NT / 64; ++w) s += sred[w];
        atomicAdd(acc, s);
    }
}

extern "C" void kernel_launch(void* const* d_in, const int* in_sizes, int n_in,
                              void* d_out, int out_size, void* d_ws, size_t ws_size,
                              hipStream_t stream) {
    const float* y_pred = (const float*)d_in[0];  // Ji
    const float* y_true = (const float*)d_in[1];  // Ii
    float* out = (float*)d_out;
    double* accp = (double*)d_ws;

    ncc_zero<<<dim3(1), dim3(1), 0, stream>>>(accp);
    dim3 grid(NB, H / TY);  // 8 x 256 = 2048 blocks -> 8 blocks/CU, 32 waves/CU at VGPR<=64
    ncc_main<<<grid, dim3(NT), 0, stream>>>(y_pred, y_true, accp);
    ncc_finalize<<<dim3(1), dim3(1), 0, stream>>>(accp, out);
}

// Round 7
// 53.072 us; speedup vs baseline: 5.7751x; 1.0393x over previous
//
#include <hip/hip_runtime.h>

#define H 1024
#define W 1024
#define NB 8
#define TY 4
#define NT 256
#define LDSW (W + 8) /* 4-col zero pad each side */

__global__ void ncc_zero(double* acc) { *acc = 0.0; }

__global__ void ncc_finalize(const double* __restrict__ acc, float* __restrict__ out) {
    out[0] = 1.0f - (float)(*acc * (1.0 / 8388608.0));  // 8*1024*1024 pixels
}

__global__ __launch_bounds__(NT) void ncc_main(
    const float* __restrict__ Jg,  // y_pred
    const float* __restrict__ Ig,  // y_true
    double* __restrict__ acc)
{
    __shared__ float vs[5][LDSW];      // vertical window sums of I, J, II, JJ, IJ
    __shared__ double sred[NT / 64];

    const int b  = blockIdx.x;
    const int y0 = blockIdx.y * TY;
    const int t  = threadIdx.x;
    const int x0 = t << 2;             // 4 output cols per thread; block spans W

    const float* __restrict__ Ib = Ig + (size_t)b * (H * W);
    const float* __restrict__ Jb = Jg + (size_t)b * (H * W);

    // zero the LDS halo pads (cols [0,4) and [W+4,W+8) of each of 5 arrays);
    // safe: publishes only touch [4, W+4), first reads happen after first barrier
    if (t < 40) {
        const int q = t >> 3, j = t & 7;
        vs[q][(j < 4) ? j : (W + 4 + (j - 4))] = 0.0f;
    }

    // per-thread vertical running column sums (own 4 cols only -> no halo redundancy)
    float sI[4]={0,0,0,0}, sJ[4]={0,0,0,0}, sII[4]={0,0,0,0}, sJJ[4]={0,0,0,0}, sIJ[4]={0,0,0,0};

    // initial vertical window: rows y0-4 .. y0+4 (clamped address, 0/1-mask the values;
    // mask commutes with squares since m*m == m)
    #pragma unroll 1
    for (int k = -4; k <= 4; ++k) {
        const int   r  = y0 + k;
        const float m  = ((unsigned)r < (unsigned)H) ? 1.0f : 0.0f;
        const int   rc = min(max(r, 0), H - 1);
        const float4 iv = *(const float4*)(Ib + (size_t)rc * W + x0);
        const float4 jv = *(const float4*)(Jb + (size_t)rc * W + x0);
        const float fi[4] = {iv.x * m, iv.y * m, iv.z * m, iv.w * m};
        const float fj[4] = {jv.x * m, jv.y * m, jv.z * m, jv.w * m};
        #pragma unroll
        for (int c = 0; c < 4; ++c) {
            sI[c] += fi[c]; sJ[c] += fj[c];
            sII[c] += fi[c] * fi[c]; sJJ[c] += fj[c] * fj[c]; sIJ[c] += fi[c] * fj[c];
        }
    }

    const float inv = 1.0f / 81.0f;
    float accv = 0.0f;

    #pragma unroll 1
    for (int y = y0; y < y0 + TY; ++y) {
        // 1) issue enter/leave row loads early; consumed only at step 4
        const int   ra  = y + 5;
        const int   rs  = y - 4;
        const float ma  = (ra < H)  ? 1.0f : 0.0f;
        const float ms  = (rs >= 0) ? 1.0f : 0.0f;
        const int   rca = min(ra, H - 1);
        const int   rcs = max(rs, 0);
        const float4 ia = *(const float4*)(Ib + (size_t)rca * W + x0);
        const float4 ja = *(const float4*)(Jb + (size_t)rca * W + x0);
        const float4 is = *(const float4*)(Ib + (size_t)rcs * W + x0);
        const float4 js = *(const float4*)(Jb + (size_t)rcs * W + x0);

        // 2) publish current vertical sums for row y
        *(float4*)&vs[0][4 + x0] = make_float4(sI[0],  sI[1],  sI[2],  sI[3]);
        *(float4*)&vs[1][4 + x0] = make_float4(sJ[0],  sJ[1],  sJ[2],  sJ[3]);
        *(float4*)&vs[2][4 + x0] = make_float4(sII[0], sII[1], sII[2], sII[3]);
        *(float4*)&vs[3][4 + x0] = make_float4(sJJ[0], sJJ[1], sJJ[2], sJJ[3]);
        *(float4*)&vs[4][4 + x0] = make_float4(sIJ[0], sIJ[1], sIJ[2], sIJ[3]);
        __syncthreads();

        // 3) horizontal 9-tap from LDS (neighbors' sums) + per-pixel cc
        float h[5][4];
        #pragma unroll
        for (int q = 0; q < 5; ++q) {
            const float4 a  = *(const float4*)&vs[q][x0];      // cols x0-4..x0-1
            const float4 bb = *(const float4*)&vs[q][x0 + 4];  // own cols
            const float4 cg = *(const float4*)&vs[q][x0 + 8];  // cols x0+4..x0+7
            float s = a.x + a.y + a.z + a.w + bb.x + bb.y + bb.z + bb.w + cg.x;
            h[q][0] = s; s += cg.y - a.x;
            h[q][1] = s; s += cg.z - a.y;
            h[q][2] = s; s += cg.w - a.z;
            h[q][3] = s;
        }
        #pragma unroll
        for (int c = 0; c < 4; ++c) {
            const float uI    = h[0][c] * inv;
            const float uJ    = h[1][c] * inv;
            const float cross = h[4][c] * inv - uI * uJ;
            const float Iv    = h[2][c] * inv - uI * uI;
            const float Jv    = h[3][c] * inv - uJ * uJ;
            accv += cross * rsqrtf(fmaxf(Iv * Jv, 1e-7f));
        }
        __syncthreads();   // all reads of vs done before next iteration's publish

        // 4) slide vertical window: add entering row, subtract leaving row
        {
            const float fa[4] = {ia.x * ma, ia.y * ma, ia.z * ma, ia.w * ma};
            const float ga[4] = {ja.x * ma, ja.y * ma, ja.z * ma, ja.w * ma};
            const float fs[4] = {is.x * ms, is.y * ms, is.z * ms, is.w * ms};
            const float gs[4] = {js.x * ms, js.y * ms, js.z * ms, js.w * ms};
            #pragma unroll
            for (int c = 0; c < 4; ++c) {
                sI[c]  += fa[c] - fs[c];
                sJ[c]  += ga[c] - gs[c];
                sII[c] += fa[c] * fa[c] - fs[c] * fs[c];
                sJJ[c] += ga[c] * ga[c] - gs[c] * gs[c];
                sIJ[c] += fa[c] * ga[c] - fs[c] * gs[c];
            }
        }
    }

    // wave reduce (64 lanes) -> LDS -> one atomic per block
    #pragma unroll
    for (int off = 32; off > 0; off >>= 1)
        accv += __shfl_down(accv, off);
    if ((t & 63) == 0)
        sred[t >> 6] = (double)accv;
    __syncthreads();
    if (t == 0) {
        double s = sred[0];
        #pragma unroll
        for (int w = 1; w < NT / 64; ++w) s += sred[w];
        atomicAdd(acc, s);
    }
}

extern "C" void kernel_launch(void* const* d_in, const int* in_sizes, int n_in,
                              void* d_out, int out_size, void* d_ws, size_t ws_size,
                              hipStream_t stream) {
    const float* y_pred = (const float*)d_in[0];  // Ji
    const float* y_true = (const float*)d_in[1];  // Ii
    float* out = (float*)d_out;
    double* accp = (double*)d_ws;

    ncc_zero<<<dim3(1), dim3(1), 0, stream>>>(accp);
    dim3 grid(NB, H / TY);  // 8 x 256 = 2048 blocks, ~7 blocks/CU (LDS 20.7KB)
    ncc_main<<<grid, dim3(NT), 0, stream>>>(y_pred, y_true, accp);
    ncc_finalize<<<dim3(1), dim3(1), 0, stream>>>(accp, out);
}

// Round 8
// 49.163 us; speedup vs baseline: 6.2342x; 1.0795x over previous
//
#include <hip/hip_runtime.h>

#define H 1024
#define W 1024
#define NB 8
#define TY 4
#define NT 256
#define WCOLS 256           /* output cols per wave */
#define LW (WCOLS + 8)      /* 264: 4-col halo each side */

__global__ void ncc_zero(double* acc) { *acc = 0.0; }

__global__ void ncc_finalize(const double* __restrict__ acc, float* __restrict__ out) {
    out[0] = 1.0f - (float)(*acc * (1.0 / 8388608.0));  // 8*1024*1024 pixels
}

__global__ __launch_bounds__(NT) void ncc_main(
    const float* __restrict__ Jg,  // y_pred
    const float* __restrict__ Ig,  // y_true
    double* __restrict__ acc)
{
    __shared__ float vs[NT / 64][5][LW];   // wave-private: I, J, II, JJ, IJ vertical sums
    __shared__ double sred[NT / 64];

    const int b    = blockIdx.x;
    const int y0   = blockIdx.y * TY;
    const int t    = threadIdx.x;
    const int w    = t >> 6;
    const int lane = t & 63;
    const int xw   = lane << 2;            // within-wave col base (0..252)
    const int x0   = (w << 8) + xw;        // global col

    const float* __restrict__ Ib = Ig + (size_t)b * (H * W);
    const float* __restrict__ Jb = Jg + (size_t)b * (H * W);

    // halo bookkeeping: lanes 0..3 maintain left halo cols, 4..7 right halo cols
    const int   wbase = w << 8;
    const bool  isH   = (lane < 8);
    const int   hc    = (lane < 4) ? (wbase - 4 + lane) : (wbase + WCOLS + (lane - 4));
    const float mh    = (isH && (unsigned)hc < (unsigned)W) ? 1.0f : 0.0f;
    const int   hcc   = min(max(hc, 0), W - 1);
    const int   hslot = (lane < 4) ? lane : (WCOLS + lane);  // 0..3 / 260..263

    // per-thread vertical running column sums (own 4 cols)
    float sI[4]={0,0,0,0}, sJ[4]={0,0,0,0}, sII[4]={0,0,0,0}, sJJ[4]={0,0,0,0}, sIJ[4]={0,0,0,0};
    // halo vertical sums (lanes 0..7 only): I, J, II, JJ, IJ
    float hs0=0, hs1=0, hs2=0, hs3=0, hs4=0;

    // initial vertical window: rows y0-4 .. y0+4 (clamped addr, 0/1 value mask)
    #pragma unroll 1
    for (int k = -4; k <= 4; ++k) {
        const int   r  = y0 + k;
        const float m  = ((unsigned)r < (unsigned)H) ? 1.0f : 0.0f;
        const int   rc = min(max(r, 0), H - 1);
        const float4 iv = *(const float4*)(Ib + (size_t)rc * W + x0);
        const float4 jv = *(const float4*)(Jb + (size_t)rc * W + x0);
        const float fi[4] = {iv.x * m, iv.y * m, iv.z * m, iv.w * m};
        const float fj[4] = {jv.x * m, jv.y * m, jv.z * m, jv.w * m};
        #pragma unroll
        for (int c = 0; c < 4; ++c) {
            sI[c] += fi[c]; sJ[c] += fj[c];
            sII[c] += fi[c] * fi[c]; sJJ[c] += fj[c] * fj[c]; sIJ[c] += fi[c] * fj[c];
        }
        if (isH) {
            const float mm = m * mh;
            const float hi = Ib[(size_t)rc * W + hcc] * mm;
            const float hj = Jb[(size_t)rc * W + hcc] * mm;
            hs0 += hi; hs1 += hj; hs2 += hi * hi; hs3 += hj * hj; hs4 += hi * hj;
        }
    }

    const float inv = 1.0f / 81.0f;
    float accv = 0.0f;

    #pragma unroll 1
    for (int y = y0; y < y0 + TY; ++y) {
        // 1) issue enter/leave global loads early (consumed only at step 4)
        const int   ra  = y + 5;
        const int   rs  = y - 4;
        const float ma  = (ra < H)  ? 1.0f : 0.0f;
        const float ms  = (rs >= 0) ? 1.0f : 0.0f;
        const int   rca = min(ra, H - 1);
        const int   rcs = max(rs, 0);
        const float4 ia = *(const float4*)(Ib + (size_t)rca * W + x0);
        const float4 ja = *(const float4*)(Jb + (size_t)rca * W + x0);
        const float4 is = *(const float4*)(Ib + (size_t)rcs * W + x0);
        const float4 js = *(const float4*)(Jb + (size_t)rcs * W + x0);
        float hia = 0, hja = 0, his = 0, hjs = 0;
        if (isH) {
            hia = Ib[(size_t)rca * W + hcc] * (ma * mh);
            hja = Jb[(size_t)rca * W + hcc] * (ma * mh);
            his = Ib[(size_t)rcs * W + hcc] * (ms * mh);
            hjs = Jb[(size_t)rcs * W + hcc] * (ms * mh);
        }

        // 2) publish current vertical sums into wave-private LDS (no barrier needed:
        //    DS ops within a wave complete in order; clobber pins compile-time order)
        *(float4*)&vs[w][0][4 + xw] = make_float4(sI[0],  sI[1],  sI[2],  sI[3]);
        *(float4*)&vs[w][1][4 + xw] = make_float4(sJ[0],  sJ[1],  sJ[2],  sJ[3]);
        *(float4*)&vs[w][2][4 + xw] = make_float4(sII[0], sII[1], sII[2], sII[3]);
        *(float4*)&vs[w][3][4 + xw] = make_float4(sJJ[0], sJJ[1], sJJ[2], sJJ[3]);
        *(float4*)&vs[w][4][4 + xw] = make_float4(sIJ[0], sIJ[1], sIJ[2], sIJ[3]);
        if (isH) {
            vs[w][0][hslot] = hs0;
            vs[w][1][hslot] = hs1;
            vs[w][2][hslot] = hs2;
            vs[w][3][hslot] = hs3;
            vs[w][4][hslot] = hs4;
        }
        asm volatile("" ::: "memory");

        // 3) horizontal 9-tap from wave LDS + per-pixel cc
        float h[5][4];
        #pragma unroll
        for (int q = 0; q < 5; ++q) {
            const float4 a  = *(const float4*)&vs[w][q][xw];      // cols -4..-1
            const float4 bb = *(const float4*)&vs[w][q][xw + 4];  // own cols
            const float4 cg = *(const float4*)&vs[w][q][xw + 8];  // cols +4..+7
            float s = a.x + a.y + a.z + a.w + bb.x + bb.y + bb.z + bb.w + cg.x;
            h[q][0] = s; s += cg.y - a.x;
            h[q][1] = s; s += cg.z - a.y;
            h[q][2] = s; s += cg.w - a.z;
            h[q][3] = s;
        }
        #pragma unroll
        for (int c = 0; c < 4; ++c) {
            const float uI    = h[0][c] * inv;
            const float uJ    = h[1][c] * inv;
            const float cross = h[4][c] * inv - uI * uJ;
            const float Iv    = h[2][c] * inv - uI * uI;
            const float Jv    = h[3][c] * inv - uJ * uJ;
            accv += cross * rsqrtf(fmaxf(Iv * Jv, 1e-7f));
        }
        asm volatile("" ::: "memory");  // reads stay above next iteration's publish

        // 4) slide vertical window (add entering row, subtract leaving row)
        {
            const float fa[4] = {ia.x * ma, ia.y * ma, ia.z * ma, ia.w * ma};
            const float ga[4] = {ja.x * ma, ja.y * ma, ja.z * ma, ja.w * ma};
            const float fs[4] = {is.x * ms, is.y * ms, is.z * ms, is.w * ms};
            const float gs[4] = {js.x * ms, js.y * ms, js.z * ms, js.w * ms};
            #pragma unroll
            for (int c = 0; c < 4; ++c) {
                sI[c]  += fa[c] - fs[c];
                sJ[c]  += ga[c] - gs[c];
                sII[c] += fa[c] * fa[c] - fs[c] * fs[c];
                sJJ[c] += ga[c] * ga[c] - gs[c] * gs[c];
                sIJ[c] += fa[c] * ga[c] - fs[c] * gs[c];
            }
        }
        if (isH) {
            hs0 += hia - his;
            hs1 += hja - hjs;
            hs2 += hia * hia - his * his;
            hs3 += hja * hja - hjs * hjs;
            hs4 += hia * hja - his * hjs;
        }
    }

    // wave reduce (64 lanes) -> LDS -> one atomic per block (cold path, barrier OK)
    #pragma unroll
    for (int off = 32; off > 0; off >>= 1)
        accv += __shfl_down(accv, off);
    if (lane == 0)
        sred[w] = (double)accv;
    __syncthreads();
    if (t == 0) {
        double s = sred[0];
        #pragma unroll
        for (int q = 1; q < NT / 64; ++q) s += sred[q];
        atomicAdd(acc, s);
    }
}

extern "C" void kernel_launch(void* const* d_in, const int* in_sizes, int n_in,
                              void* d_out, int out_size, void* d_ws, size_t ws_size,
                              hipStream_t stream) {
    const float* y_pred = (const float*)d_in[0];  // Ji
    const float* y_true = (const float*)d_in[1];  // Ii
    float* out = (float*)d_out;
    double* accp = (double*)d_ws;

    ncc_zero<<<dim3(1), dim3(1), 0, stream>>>(accp);
    dim3 grid(NB, H / TY);  // 8 x 256 = 2048 blocks; zero barriers in hot loop
    ncc_main<<<grid, dim3(NT), 0, stream>>>(y_pred, y_true, accp);
    ncc_finalize<<<dim3(1), dim3(1), 0, stream>>>(accp, out);
}

// Round 9
// 42.938 us; speedup vs baseline: 7.1380x; 1.1450x over previous
//
#include <hip/hip_runtime.h>

#define H 1024
#define W 1024
#define NB 8
#define TY 8
#define NT 256
#define WCOLS 256           /* output cols per wave */
#define LW (WCOLS + 8)      /* 264: 4-col halo each side */

__global__ void ncc_zero(double* acc) { *acc = 0.0; }

__global__ void ncc_finalize(const double* __restrict__ acc, float* __restrict__ out) {
    out[0] = 1.0f - (float)(*acc * (1.0 / 8388608.0));  // 8*1024*1024 pixels
}

__global__ __launch_bounds__(NT) void ncc_main(
    const float* __restrict__ Jg,  // y_pred
    const float* __restrict__ Ig,  // y_true
    double* __restrict__ acc)
{
    __shared__ float vs[NT / 64][5][LW];   // wave-private vertical sums: I,J,II,JJ,IJ
    __shared__ double sred[NT / 64];

    const int b    = blockIdx.x;
    const int y0   = blockIdx.y * TY;
    const int t    = threadIdx.x;
    const int w    = t >> 6;
    const int lane = t & 63;
    const int xw   = lane << 2;            // within-wave col base (0..252)
    const int x0   = (w << 8) + xw;        // global col

    const float* __restrict__ Ib = Ig + (size_t)b * (H * W);
    const float* __restrict__ Jb = Jg + (size_t)b * (H * W);

    // halo: lanes 0..3 left halo cols, lanes 4..7 right halo cols (one scalar col each)
    const int   wbase = w << 8;
    const bool  isH   = (lane < 8);
    const int   hc    = (lane < 4) ? (wbase - 4 + lane) : (wbase + WCOLS + (lane - 4));
    const float mh    = (isH && (unsigned)hc < (unsigned)W) ? 1.0f : 0.0f;
    const int   hcc   = min(max(hc, 0), W - 1);
    const int   hslot = (lane < 4) ? lane : (WCOLS + lane);  // 0..3 / 260..263

    float sI[4]={0,0,0,0}, sJ[4]={0,0,0,0}, sII[4]={0,0,0,0}, sJJ[4]={0,0,0,0}, sIJ[4]={0,0,0,0};
    float hs0=0, hs1=0, hs2=0, hs3=0, hs4=0;

    // ---- pipelined init: rows y0-4 .. y0+4, one row ahead in flight ----
    float4 civ, cjv; float chi = 0, chj = 0, cm;
    {
        const int r  = y0 - 4;
        cm = ((unsigned)r < (unsigned)H) ? 1.0f : 0.0f;
        const int rc = min(max(r, 0), H - 1);
        civ = *(const float4*)(Ib + (size_t)rc * W + x0);
        cjv = *(const float4*)(Jb + (size_t)rc * W + x0);
        if (isH) { chi = Ib[(size_t)rc * W + hcc]; chj = Jb[(size_t)rc * W + hcc]; }
    }
    #pragma unroll 1
    for (int k = -4; k <= 4; ++k) {
        // prefetch next row (dummy re-load of last row on final iter)
        const int   rn  = y0 + ((k < 4) ? (k + 1) : 4);
        const float nm  = ((unsigned)(y0 + k + 1) < (unsigned)H) ? 1.0f : 0.0f;
        const int   rnc = min(max(rn, 0), H - 1);
        float4 niv = *(const float4*)(Ib + (size_t)rnc * W + x0);
        float4 njv = *(const float4*)(Jb + (size_t)rnc * W + x0);
        float  nhi = 0, nhj = 0;
        if (isH) { nhi = Ib[(size_t)rnc * W + hcc]; nhj = Jb[(size_t)rnc * W + hcc]; }

        // fold current row
        {
            const float fi[4] = {civ.x * cm, civ.y * cm, civ.z * cm, civ.w * cm};
            const float fj[4] = {cjv.x * cm, cjv.y * cm, cjv.z * cm, cjv.w * cm};
            #pragma unroll
            for (int c = 0; c < 4; ++c) {
                sI[c] += fi[c]; sJ[c] += fj[c];
                sII[c] += fi[c] * fi[c]; sJJ[c] += fj[c] * fj[c]; sIJ[c] += fi[c] * fj[c];
            }
            const float mm = cm * mh;
            const float hi = chi * mm, hj = chj * mm;
            hs0 += hi; hs1 += hj; hs2 += hi * hi; hs3 += hj * hj; hs4 += hi * hj;
        }
        civ = niv; cjv = njv; chi = nhi; chj = nhj; cm = nm;
    }

    // ---- prologue prefetch for the first slide (window y0 -> y0+1) ----
    float4 pia, pja, pis, pjs; float phia = 0, phja = 0, phis = 0, phjs = 0; float pma, pms;
    {
        const int ra = y0 + 5, rs = y0 - 4;
        pma = (ra < H) ? 1.0f : 0.0f;
        pms = (rs >= 0) ? 1.0f : 0.0f;
        const int rca = min(ra, H - 1), rcs = max(rs, 0);
        pia = *(const float4*)(Ib + (size_t)rca * W + x0);
        pja = *(const float4*)(Jb + (size_t)rca * W + x0);
        pis = *(const float4*)(Ib + (size_t)rcs * W + x0);
        pjs = *(const float4*)(Jb + (size_t)rcs * W + x0);
        if (isH) {
            phia = Ib[(size_t)rca * W + hcc]; phja = Jb[(size_t)rca * W + hcc];
            phis = Ib[(size_t)rcs * W + hcc]; phjs = Jb[(size_t)rcs * W + hcc];
        }
    }

    const float inv = 1.0f / 81.0f;
    float accv = 0.0f;

    #pragma unroll 1
    for (int y = y0; y < y0 + TY; ++y) {
        // 1) publish window(y)
        *(float4*)&vs[w][0][4 + xw] = make_float4(sI[0],  sI[1],  sI[2],  sI[3]);
        *(float4*)&vs[w][1][4 + xw] = make_float4(sJ[0],  sJ[1],  sJ[2],  sJ[3]);
        *(float4*)&vs[w][2][4 + xw] = make_float4(sII[0], sII[1], sII[2], sII[3]);
        *(float4*)&vs[w][3][4 + xw] = make_float4(sJJ[0], sJJ[1], sJJ[2], sJJ[3]);
        *(float4*)&vs[w][4][4 + xw] = make_float4(sIJ[0], sIJ[1], sIJ[2], sIJ[3]);
        if (isH) {
            vs[w][0][hslot] = hs0; vs[w][1][hslot] = hs1; vs[w][2][hslot] = hs2;
            vs[w][3][hslot] = hs3; vs[w][4][hslot] = hs4;
        }
        asm volatile("" ::: "memory");

        // 2) issue halo reads only (own cols stay in registers); in-wave DS is in-order
        float4 a0 = *(const float4*)&vs[w][0][xw], c0 = *(const float4*)&vs[w][0][xw + 8];
        float4 a1 = *(const float4*)&vs[w][1][xw], c1 = *(const float4*)&vs[w][1][xw + 8];
        float4 a2 = *(const float4*)&vs[w][2][xw], c2 = *(const float4*)&vs[w][2][xw + 8];
        float4 a3 = *(const float4*)&vs[w][3][xw], c3 = *(const float4*)&vs[w][3][xw + 8];
        float4 a4 = *(const float4*)&vs[w][4][xw], c4 = *(const float4*)&vs[w][4][xw + 8];
        asm volatile("" ::: "memory");

        // 3) snapshot own totals of window(y) before sliding
        const float T0 = sI[0]  + sI[1]  + sI[2]  + sI[3];
        const float T1 = sJ[0]  + sJ[1]  + sJ[2]  + sJ[3];
        const float T2 = sII[0] + sII[1] + sII[2] + sII[3];
        const float T3 = sJJ[0] + sJJ[1] + sJJ[2] + sJJ[3];
        const float T4 = sIJ[0] + sIJ[1] + sIJ[2] + sIJ[3];

        // 4) slide sums to window(y+1) using prefetched rows (covers the LDS round trip)
        {
            const float fa[4] = {pia.x * pma, pia.y * pma, pia.z * pma, pia.w * pma};
            const float ga[4] = {pja.x * pma, pja.y * pma, pja.z * pma, pja.w * pma};
            const float fs[4] = {pis.x * pms, pis.y * pms, pis.z * pms, pis.w * pms};
            const float gs[4] = {pjs.x * pms, pjs.y * pms, pjs.z * pms, pjs.w * pms};
            #pragma unroll
            for (int c = 0; c < 4; ++c) {
                sI[c]  += fa[c] - fs[c];
                sJ[c]  += ga[c] - gs[c];
                sII[c] += fa[c] * fa[c] - fs[c] * fs[c];
                sJJ[c] += ga[c] * ga[c] - gs[c] * gs[c];
                sIJ[c] += fa[c] * ga[c] - fs[c] * gs[c];
            }
            const float hia = phia * (pma * mh), hja = phja * (pma * mh);
            const float his = phis * (pms * mh), hjs = phjs * (pms * mh);
            hs0 += hia - his;
            hs1 += hja - hjs;
            hs2 += hia * hia - his * his;
            hs3 += hja * hja - hjs * hjs;
            hs4 += hia * hja - his * hjs;
        }

        // 5) prefetch rows for the next slide (window y+1 -> y+2)
        {
            const int ra = y + 6, rs = y - 3;
            pma = (ra < H) ? 1.0f : 0.0f;
            pms = (rs >= 0) ? 1.0f : 0.0f;
            const int rca = min(ra, H - 1), rcs = max(rs, 0);
            pia = *(const float4*)(Ib + (size_t)rca * W + x0);
            pja = *(const float4*)(Jb + (size_t)rca * W + x0);
            pis = *(const float4*)(Ib + (size_t)rcs * W + x0);
            pjs = *(const float4*)(Jb + (size_t)rcs * W + x0);
            if (isH) {
                phia = Ib[(size_t)rca * W + hcc]; phja = Jb[(size_t)rca * W + hcc];
                phis = Ib[(size_t)rcs * W + hcc]; phjs = Jb[(size_t)rcs * W + hcc];
            }
        }

        // 6) combine halo + own totals -> 9-tap sums; per-pixel cc for row y
        float h[5][4];
        {
            const float4 aa[5] = {a0, a1, a2, a3, a4};
            const float4 cc4[5] = {c0, c1, c2, c3, c4};
            const float  TT[5] = {T0, T1, T2, T3, T4};
            #pragma unroll
            for (int q = 0; q < 5; ++q) {
                const float4 a  = aa[q];
                const float4 cg = cc4[q];
                float s = a.x + a.y + a.z + a.w + cg.x + TT[q];
                h[q][0] = s; s += cg.y - a.x;
                h[q][1] = s; s += cg.z - a.y;
                h[q][2] = s; s += cg.w - a.z;
                h[q][3] = s;
            }
        }
        #pragma unroll
        for (int c = 0; c < 4; ++c) {
            const float uI    = h[0][c] * inv;
            const float uJ    = h[1][c] * inv;
            const float cross = h[4][c] * inv - uI * uJ;
            const float Iv    = h[2][c] * inv - uI * uI;
            const float Jv    = h[3][c] * inv - uJ * uJ;
            accv += cross * rsqrtf(fmaxf(Iv * Jv, 1e-7f));
        }
    }

    // wave reduce (64 lanes) -> LDS -> one atomic per block (cold path)
    #pragma unroll
    for (int off = 32; off > 0; off >>= 1)
        accv += __shfl_down(accv, off);
    if (lane == 0)
        sred[w] = (double)accv;
    __syncthreads();
    if (t == 0) {
        double s = sred[0];
        #pragma unroll
        for (int q = 1; q < NT / 64; ++q) s += sred[q];
        atomicAdd(acc, s);
    }
}

extern "C" void kernel_launch(void* const* d_in, const int* in_sizes, int n_in,
                              void* d_out, int out_size, void* d_ws, size_t ws_size,
                              hipStream_t stream) {
    const float* y_pred = (const float*)d_in[0];  // Ji
    const float* y_true = (const float*)d_in[1];  // Ii
    float* out = (float*)d_out;
    double* accp = (double*)d_ws;

    ncc_zero<<<dim3(1), dim3(1), 0, stream>>>(accp);
    dim3 grid(NB, H / TY);  // 8 x 128 = 1024 blocks; zero barriers, software-pipelined
    ncc_main<<<grid, dim3(NT), 0, stream>>>(y_pred, y_true, accp);
    ncc_finalize<<<dim3(1), dim3(1), 0, stream>>>(accp, out);
}